// Round 1
// baseline (132.909 us; speedup 1.0000x reference)
//
#include <hip/hip_runtime.h>

typedef short bf16x8 __attribute__((ext_vector_type(8)));
typedef float f32x4 __attribute__((ext_vector_type(4)));

#define AS1 __attribute__((address_space(1)))
#define AS3 __attribute__((address_space(3)))

__device__ __forceinline__ unsigned short f2bf(float f) {
  unsigned int u = __builtin_bit_cast(unsigned int, f);
  return (unsigned short)((u + 0x8000u) >> 16);
}

// ---------------------------------------------------------------------------
// Prep: W2 [J][256][256] f32  ->  w2t [J][4 slices][32KB] bf16, layout per
// slice: byte(n,k) = n*128 + ((2k) ^ ((n&7)<<4)), n in [0,256), k in [0,64).
// This is the exact linear image the main kernel stages with global_load_lds,
// giving bank-conflict-free (2-way) ds_read_b128 B-fragment reads.
// ---------------------------------------------------------------------------
__global__ __launch_bounds__(256) void prep_w2t(const float* __restrict__ W2,
                                                unsigned char* __restrict__ w2t) {
  const int s = blockIdx.x;   // k-slice 0..3
  const int j = blockIdx.y;   // slot 0..31
  const int t = threadIdx.x;  // 0..255
  __shared__ unsigned short lds[64 * 264];  // [k][n] bf16, padded

  const float* src = W2 + (((size_t)j * 256 + (size_t)s * 64) * 256);
#pragma unroll
  for (int i = 0; i < 16; ++i) {
    const int idx4 = i * 256 + t;        // 0..4095 float4s
    const int k = idx4 >> 6;             // 0..63
    const int n = (idx4 & 63) << 2;      // 0..252
    const float4 v = *reinterpret_cast<const float4*>(src + k * 256 + n);
    unsigned short* p = &lds[k * 264 + n];
    p[0] = f2bf(v.x); p[1] = f2bf(v.y); p[2] = f2bf(v.z); p[3] = f2bf(v.w);
  }
  __syncthreads();

  unsigned char* dst = w2t + (((size_t)j * 4 + s) << 15);
#pragma unroll
  for (int i = 0; i < 8; ++i) {
    const int slot = i * 256 + t;        // 0..2047 16B slots
    const int n = slot >> 3;
    const int u = slot & 7;
    const int kslot = u ^ (n & 7);       // slot content: k = kslot*8 .. +8
    unsigned int w[4];
#pragma unroll
    for (int q = 0; q < 4; ++q) {
      const unsigned int lo = lds[(kslot * 8 + q * 2 + 0) * 264 + n];
      const unsigned int hi = lds[(kslot * 8 + q * 2 + 1) * 264 + n];
      w[q] = lo | (hi << 16);
    }
    *reinterpret_cast<uint4*>(dst + slot * 16) = make_uint4(w[0], w[1], w[2], w[3]);
  }
}

// ---------------------------------------------------------------------------
// Main fused kernel: 8 waves (wm=wid>>1 row-group, wn=wid&1 col-half).
// Block tile: 128 rows x 256 cols, one slot j. K=256 in 4 LDS slices of 64.
// ---------------------------------------------------------------------------
__device__ __forceinline__ void stage_slice(unsigned char* ldsbuf,
                                            const unsigned char* gsrc,
                                            int wid, int lane) {
#pragma unroll
  for (int it = 0; it < 4; ++it) {
    const int off = (it * 8 + wid) << 10;  // 1KB per wave-call
    __builtin_amdgcn_global_load_lds(
        (const AS1 unsigned int*)(gsrc + off + lane * 16),
        (AS3 unsigned int*)(ldsbuf + off), 16, 0, 0);
  }
}

__global__ __launch_bounds__(512, 2) void fused_mlp(
    const float* __restrict__ input, const int* __restrict__ validity,
    const float* __restrict__ W1, const float* __restrict__ b1,
    const float* __restrict__ b2, const unsigned char* __restrict__ w2t,
    float* __restrict__ out) {
  __shared__ unsigned char smem[65536];  // 2 x 32KB double buffer
  const int bt = blockIdx.x;   // row tile 0..63
  const int j  = blockIdx.y;   // slot 0..31
  const int tid = threadIdx.x;
  const int wid = tid >> 6;
  const int lane = tid & 63;
  const int wm = wid >> 1, wn = wid & 1;
  const int l15 = lane & 15, lg = lane >> 4;

  const unsigned char* w2tj = w2t + ((size_t)j << 17);

  // kick off slice 0 staging; its latency hides under the layer-1 compute
  stage_slice(smem, w2tj, wid, lane);

  // ---- layer 1 + silu, computed directly as MFMA A-fragments ----
  const float* W1j = W1 + (j << 10);
  const float* b1j = b1 + (j << 8);
  const int rowbase = (bt << 7) + (wm << 5);

  float xr[2][4];
#pragma unroll
  for (int mf = 0; mf < 2; ++mf) {
    const int row = rowbase + mf * 16 + l15;
    const float* ip = input + ((size_t)row * 32 + j) * 3;
    xr[mf][0] = ip[0]; xr[mf][1] = ip[1]; xr[mf][2] = ip[2];
    xr[mf][3] = (float)validity[row * 32 + j];
  }

  bf16x8 afrag[2][8];  // [m-frag][k-frag]; lane holds H[row=l15][k=kf*32+lg*8+i]
#pragma unroll
  for (int kf = 0; kf < 8; ++kf) {
    const int kb = kf * 32 + lg * 8;
    float w1v[4][8];
#pragma unroll
    for (int c = 0; c < 4; ++c) {
      const float4 lo = *reinterpret_cast<const float4*>(W1j + c * 256 + kb);
      const float4 hi = *reinterpret_cast<const float4*>(W1j + c * 256 + kb + 4);
      w1v[c][0] = lo.x; w1v[c][1] = lo.y; w1v[c][2] = lo.z; w1v[c][3] = lo.w;
      w1v[c][4] = hi.x; w1v[c][5] = hi.y; w1v[c][6] = hi.z; w1v[c][7] = hi.w;
    }
    float b1v[8];
    const float4 blo = *reinterpret_cast<const float4*>(b1j + kb);
    const float4 bhi = *reinterpret_cast<const float4*>(b1j + kb + 4);
    b1v[0] = blo.x; b1v[1] = blo.y; b1v[2] = blo.z; b1v[3] = blo.w;
    b1v[4] = bhi.x; b1v[5] = bhi.y; b1v[6] = bhi.z; b1v[7] = bhi.w;
#pragma unroll
    for (int mf = 0; mf < 2; ++mf) {
#pragma unroll
      for (int i = 0; i < 8; ++i) {
        float z = b1v[i];
        z = fmaf(xr[mf][0], w1v[0][i], z);
        z = fmaf(xr[mf][1], w1v[1][i], z);
        z = fmaf(xr[mf][2], w1v[2][i], z);
        z = fmaf(xr[mf][3], w1v[3][i], z);
        const float h = z * __builtin_amdgcn_rcpf(1.0f + __expf(-z));
        afrag[mf][kf][i] = (short)f2bf(h);
      }
    }
  }

  f32x4 acc[2][8];
#pragma unroll
  for (int mf = 0; mf < 2; ++mf)
#pragma unroll
    for (int nf = 0; nf < 8; ++nf) acc[mf][nf] = f32x4{0.f, 0.f, 0.f, 0.f};

  // ---- K loop: 4 slices of 64, double-buffered, counted vmcnt ----
#pragma unroll
  for (int s = 0; s < 4; ++s) {
    if (s < 3)
      stage_slice(smem + (((s + 1) & 1) << 15), w2tj + ((size_t)(s + 1) << 15),
                  wid, lane);
    if (s < 3) asm volatile("s_waitcnt vmcnt(4)" ::: "memory");
    else       asm volatile("s_waitcnt vmcnt(0)" ::: "memory");
    __builtin_amdgcn_s_barrier();
    const unsigned char* buf = smem + ((s & 1) << 15);
#pragma unroll
    for (int kf2 = 0; kf2 < 2; ++kf2) {
#pragma unroll
      for (int nf = 0; nf < 8; ++nf) {
        const int n = (wn << 7) + (nf << 4) + l15;
        const int koff = ((kf2 << 6) + (lg << 4)) ^ ((n & 7) << 4);
        const bf16x8 bfrag =
            *reinterpret_cast<const bf16x8*>(buf + n * 128 + koff);
        acc[0][nf] = __builtin_amdgcn_mfma_f32_16x16x32_bf16(
            afrag[0][s * 2 + kf2], bfrag, acc[0][nf], 0, 0, 0);
        acc[1][nf] = __builtin_amdgcn_mfma_f32_16x16x32_bf16(
            afrag[1][s * 2 + kf2], bfrag, acc[1][nf], 0, 0, 0);
      }
    }
    asm volatile("" ::: "memory");
    __builtin_amdgcn_s_barrier();
  }

  // ---- epilogue: + b2, store f32 ----
  const float* b2j = b2 + (j << 8);
#pragma unroll
  for (int nf = 0; nf < 8; ++nf) {
    const int n = (wn << 7) + (nf << 4) + l15;
    const float bias = b2j[n];
    const size_t colbase = (size_t)(j << 8) + n;
#pragma unroll
    for (int mf = 0; mf < 2; ++mf) {
      const int r0 = rowbase + mf * 16 + (lg << 2);
#pragma unroll
      for (int r = 0; r < 4; ++r) {
        out[(size_t)(r0 + r) * 8192 + colbase] = acc[mf][nf][r] + bias;
      }
    }
  }
}

extern "C" void kernel_launch(void* const* d_in, const int* in_sizes, int n_in,
                              void* d_out, int out_size, void* d_ws, size_t ws_size,
                              hipStream_t stream) {
  (void)in_sizes; (void)n_in; (void)out_size; (void)ws_size;
  const float* input    = (const float*)d_in[0];
  const int*   validity = (const int*)d_in[1];
  const float* W1       = (const float*)d_in[2];
  const float* b1       = (const float*)d_in[3];
  const float* W2       = (const float*)d_in[4];
  const float* b2       = (const float*)d_in[5];
  float* out = (float*)d_out;
  unsigned char* w2t = (unsigned char*)d_ws;  // 4 MB: J*4 slices * 32KB

  prep_w2t<<<dim3(4, 32), 256, 0, stream>>>(W2, w2t);
  fused_mlp<<<dim3(64, 32), 512, 0, stream>>>(input, validity, W1, b1, b2, w2t, out);
}

// Round 2
// 105.282 us; speedup vs baseline: 1.2624x; 1.2624x over previous
//
#include <hip/hip_runtime.h>

typedef short bf16x8 __attribute__((ext_vector_type(8)));
typedef float f32x4 __attribute__((ext_vector_type(4)));

#define AS1 __attribute__((address_space(1)))
#define AS3 __attribute__((address_space(3)))

__device__ __forceinline__ unsigned short f2bf(float f) {
  unsigned int u = __builtin_bit_cast(unsigned int, f);
  return (unsigned short)((u + 0x8000u) >> 16);
}

// ---------------------------------------------------------------------------
// Prep: W2 [J][256][256] f32 -> w2t [J][4 slices][32KB] bf16, layout per
// slice: byte(n,k) = n*128 + ((2k) ^ ((n&7)<<4)), n in [0,256), k in [0,64).
// ---------------------------------------------------------------------------
__global__ __launch_bounds__(256) void prep_w2t(const float* __restrict__ W2,
                                                unsigned char* __restrict__ w2t) {
  const int s = blockIdx.x;   // k-slice 0..3
  const int j = blockIdx.y;   // slot 0..31
  const int t = threadIdx.x;  // 0..255
  __shared__ unsigned short lds[64 * 264];  // [k][n] bf16, padded

  const float* src = W2 + (((size_t)j * 256 + (size_t)s * 64) * 256);
#pragma unroll
  for (int i = 0; i < 16; ++i) {
    const int idx4 = i * 256 + t;        // 0..4095 float4s
    const int k = idx4 >> 6;             // 0..63
    const int n = (idx4 & 63) << 2;      // 0..252
    const float4 v = *reinterpret_cast<const float4*>(src + k * 256 + n);
    unsigned short* p = &lds[k * 264 + n];
    p[0] = f2bf(v.x); p[1] = f2bf(v.y); p[2] = f2bf(v.z); p[3] = f2bf(v.w);
  }
  __syncthreads();

  unsigned char* dst = w2t + (((size_t)j * 4 + s) << 15);
#pragma unroll
  for (int i = 0; i < 8; ++i) {
    const int slot = i * 256 + t;        // 0..2047 16B slots
    const int n = slot >> 3;
    const int u = slot & 7;
    const int kslot = u ^ (n & 7);       // slot content: k = kslot*8 .. +8
    unsigned int w[4];
#pragma unroll
    for (int q = 0; q < 4; ++q) {
      const unsigned int lo = lds[(kslot * 8 + q * 2 + 0) * 264 + n];
      const unsigned int hi = lds[(kslot * 8 + q * 2 + 1) * 264 + n];
      w[q] = lo | (hi << 16);
    }
    *reinterpret_cast<uint4*>(dst + slot * 16) = make_uint4(w[0], w[1], w[2], w[3]);
  }
}

// ---------------------------------------------------------------------------
// Main fused kernel. 512 threads = 8 waves (wm=wid>>1, wn=wid&1).
// Block tile 128 rows x 256 cols, one slot j. K=256 in 4 LDS slices of 64,
// double-buffered with counted vmcnt. Layer-1 A-fragments computed just-in-
// time per slice (VALU overlaps other waves' MFMA). W1/b1 live in LDS.
// ---------------------------------------------------------------------------
__device__ __forceinline__ void stage_slice(unsigned char* ldsbuf,
                                            const unsigned char* gsrc,
                                            int wid, int lane) {
#pragma unroll
  for (int it = 0; it < 4; ++it) {
    const int off = (it * 8 + wid) << 10;  // 1KB per wave-call
    __builtin_amdgcn_global_load_lds(
        (const AS1 unsigned int*)(gsrc + off + lane * 16),
        (AS3 unsigned int*)(ldsbuf + off), 16, 0, 0);
  }
}

__global__ __launch_bounds__(512, 4) void fused_mlp(
    const float* __restrict__ input, const int* __restrict__ validity,
    const float* __restrict__ W1, const float* __restrict__ b1,
    const float* __restrict__ b2, const unsigned char* __restrict__ w2t,
    float* __restrict__ out) {
  // 2 x 32KB W2 double buffer + 4KB W1 + 1KB b1
  __shared__ __align__(16) unsigned char smem[70656];
  const int bt = blockIdx.x;   // row tile 0..63
  const int j  = blockIdx.y;   // slot 0..31
  const int tid = threadIdx.x;
  const int wid = tid >> 6;
  const int lane = tid & 63;
  const int wm = wid >> 1, wn = wid & 1;
  const int l15 = lane & 15, lg = lane >> 4;

  const unsigned char* w2tj = w2t + ((size_t)j << 17);
  const int rowbase = (bt << 7) + (wm << 5);

  // ---- prologue VMEM (all issued before the slice stages) ----
  float xr[2][4];
#pragma unroll
  for (int mf = 0; mf < 2; ++mf) {
    const int row = rowbase + mf * 16 + l15;
    const float* ip = input + ((size_t)row * 32 + j) * 3;
    xr[mf][0] = ip[0]; xr[mf][1] = ip[1]; xr[mf][2] = ip[2];
    xr[mf][3] = (float)validity[row * 32 + j];
  }
  const float* b2j = b2 + (j << 8);
  float b2v[8];
#pragma unroll
  for (int nf = 0; nf < 8; ++nf) b2v[nf] = b2j[(wn << 7) + (nf << 4) + l15];

  const float* W1j = W1 + (j << 10);
  const float* b1j = b1 + (j << 8);
  float4 wstage = make_float4(0.f, 0.f, 0.f, 0.f);
  if (tid < 320) {
    const float* src = (tid < 256) ? (W1j + (tid << 2)) : (b1j + ((tid - 256) << 2));
    wstage = *reinterpret_cast<const float4*>(src);
  }

  // ---- stage W2 slices 0 and 1 (the ONLY VMEM after this point: stages) ----
  stage_slice(smem, w2tj, wid, lane);
  stage_slice(smem + 32768, w2tj + 32768, wid, lane);

  // ---- W1/b1 -> LDS ----
  if (tid < 320) {
    *reinterpret_cast<float4*>(smem + 65536 + (tid << 4)) = wstage;
  }

  // acc init = bias (saves zero-init + epilogue add)
  f32x4 acc[2][8];
#pragma unroll
  for (int nf = 0; nf < 8; ++nf) {
    const float b = b2v[nf];
    acc[0][nf] = f32x4{b, b, b, b};
    acc[1][nf] = f32x4{b, b, b, b};
  }

  asm volatile("s_waitcnt lgkmcnt(0)" ::: "memory");  // W1 ds_writes visible
  __builtin_amdgcn_s_barrier();

  // ---- precomputed LDS bases (all loop reads use immediate offsets) ----
  const unsigned char* w1base = smem + 65536 + (lg << 5);
  const int q = (lg << 4) ^ ((l15 & 7) << 4);
  const unsigned char* rA = smem + ((wn << 7) + l15) * 128 + q;         // kf2=0
  const unsigned char* rB = smem + ((wn << 7) + l15) * 128 + (q ^ 64);  // kf2=1

  // ---- K loop: slice s of 64, steady-state vmcnt(4) keeps next stage in flight
#pragma unroll
  for (int s = 0; s < 4; ++s) {
    // JIT layer-1: A-fragments for kf = 2s, 2s+1 (VALU; overlaps other waves'
    // MFMA and the in-flight stage of slice s)
    bf16x8 af[2][2];  // [kf2][mf]
#pragma unroll
    for (int kf2 = 0; kf2 < 2; ++kf2) {
      const int kf = 2 * s + kf2;
#pragma unroll
      for (int half = 0; half < 2; ++half) {
        const int im = kf * 128 + half * 16;
        const f32x4 w0 = *reinterpret_cast<const f32x4*>(w1base + 0 * 1024 + im);
        const f32x4 w1v = *reinterpret_cast<const f32x4*>(w1base + 1 * 1024 + im);
        const f32x4 w2v = *reinterpret_cast<const f32x4*>(w1base + 2 * 1024 + im);
        const f32x4 w3v = *reinterpret_cast<const f32x4*>(w1base + 3 * 1024 + im);
        const f32x4 bb = *reinterpret_cast<const f32x4*>(w1base + 4096 + im);
#pragma unroll
        for (int mf = 0; mf < 2; ++mf) {
#pragma unroll
          for (int i = 0; i < 4; ++i) {
            float z = bb[i];
            z = fmaf(xr[mf][0], w0[i], z);
            z = fmaf(xr[mf][1], w1v[i], z);
            z = fmaf(xr[mf][2], w2v[i], z);
            z = fmaf(xr[mf][3], w3v[i], z);
            const float h = z * __builtin_amdgcn_rcpf(1.0f + __expf(-z));
            af[kf2][mf][half * 4 + i] = (short)f2bf(h);
          }
        }
      }
    }

    // slice s staged? (exactly 4 newer VMEM ops = stage of slice s+1)
    if (s < 3) asm volatile("s_waitcnt vmcnt(4)" ::: "memory");
    else       asm volatile("s_waitcnt vmcnt(0)" ::: "memory");
    __builtin_amdgcn_s_barrier();

    const int immS = (s & 1) << 15;
#pragma unroll
    for (int nf = 0; nf < 8; ++nf) {
      const int im = immS + nf * 2048;
      const bf16x8 bf0 = *reinterpret_cast<const bf16x8*>(rA + im);
      const bf16x8 bf1 = *reinterpret_cast<const bf16x8*>(rB + im);
      acc[0][nf] = __builtin_amdgcn_mfma_f32_16x16x32_bf16(af[0][0], bf0, acc[0][nf], 0, 0, 0);
      acc[1][nf] = __builtin_amdgcn_mfma_f32_16x16x32_bf16(af[0][1], bf0, acc[1][nf], 0, 0, 0);
      acc[0][nf] = __builtin_amdgcn_mfma_f32_16x16x32_bf16(af[1][0], bf1, acc[0][nf], 0, 0, 0);
      acc[1][nf] = __builtin_amdgcn_mfma_f32_16x16x32_bf16(af[1][1], bf1, acc[1][nf], 0, 0, 0);
    }

    // all ds_reads of buf[s&1] landed in regs before we allow restaging
    asm volatile("s_waitcnt lgkmcnt(0)" ::: "memory");
    __builtin_amdgcn_s_barrier();
    if (s < 2)
      stage_slice(smem + ((s & 1) << 15), w2tj + ((size_t)(s + 2) << 15), wid, lane);
  }

  // ---- epilogue: pure stores, immediate column offsets ----
  const size_t colbase = ((size_t)j << 8) + (wn << 7) + l15;
#pragma unroll
  for (int mf = 0; mf < 2; ++mf) {
#pragma unroll
    for (int r = 0; r < 4; ++r) {
      const int row = rowbase + mf * 16 + (lg << 2) + r;
      float* p = out + (size_t)row * 8192 + colbase;
#pragma unroll
      for (int nf = 0; nf < 8; ++nf) p[nf << 4] = acc[mf][nf][r];
    }
  }
}

extern "C" void kernel_launch(void* const* d_in, const int* in_sizes, int n_in,
                              void* d_out, int out_size, void* d_ws, size_t ws_size,
                              hipStream_t stream) {
  (void)in_sizes; (void)n_in; (void)out_size; (void)ws_size;
  const float* input    = (const float*)d_in[0];
  const int*   validity = (const int*)d_in[1];
  const float* W1       = (const float*)d_in[2];
  const float* b1       = (const float*)d_in[3];
  const float* W2       = (const float*)d_in[4];
  const float* b2       = (const float*)d_in[5];
  float* out = (float*)d_out;
  unsigned char* w2t = (unsigned char*)d_ws;  // 4 MB: J*4 slices * 32KB

  prep_w2t<<<dim3(4, 32), 256, 0, stream>>>(W2, w2t);
  fused_mlp<<<dim3(64, 32), 512, 0, stream>>>(input, validity, W1, b1, b2, w2t, out);
}

// Round 4
// 98.414 us; speedup vs baseline: 1.3505x; 1.0698x over previous
//
#include <hip/hip_runtime.h>

typedef short bf16x8 __attribute__((ext_vector_type(8)));
typedef float f32x4 __attribute__((ext_vector_type(4)));

#define AS1 __attribute__((address_space(1)))
#define AS3 __attribute__((address_space(3)))

__device__ __forceinline__ unsigned short f2bf(float f) {
  unsigned int u = __builtin_bit_cast(unsigned int, f);
  return (unsigned short)((u + 0x8000u) >> 16);
}

// ---------------------------------------------------------------------------
// Prep: W2 [J][256][256] f32 -> w2t [j*2+ch][4 slices][128 cols][128B] bf16,
// swizzled: byte(n, kk) = n*128 + ((2*kk) ^ ((n&7)<<4)), n in [0,128),
// kk in [0,64). Linear image for global_load_lds + conflict-free ds_read_b128.
// ---------------------------------------------------------------------------
__global__ __launch_bounds__(256) void prep_w2t(const float* __restrict__ W2,
                                                unsigned char* __restrict__ w2t) {
  const int s = blockIdx.x;    // k-slice 0..3
  const int jc = blockIdx.y;   // j*2+ch
  const int j = jc >> 1, ch = jc & 1;
  const int t = threadIdx.x;
  __shared__ unsigned short lds[64 * 136];  // [kk][n], padded

  const float* src = W2 + (size_t)j * 65536 + (size_t)(s * 64) * 256 + ch * 128;
#pragma unroll
  for (int i = 0; i < 8; ++i) {
    const int idx4 = i * 256 + t;        // 2048 float4s = 64kk x 128n
    const int kk = idx4 >> 5;
    const int n4 = (idx4 & 31) << 2;
    const float4 v = *reinterpret_cast<const float4*>(src + kk * 256 + n4);
    unsigned short* p = &lds[kk * 136 + n4];
    p[0] = f2bf(v.x); p[1] = f2bf(v.y); p[2] = f2bf(v.z); p[3] = f2bf(v.w);
  }
  __syncthreads();

  unsigned char* dst = w2t + (((size_t)jc * 4 + s) << 14);
#pragma unroll
  for (int i = 0; i < 4; ++i) {
    const int slot = i * 256 + t;        // 1024 16B slots
    const int n = slot >> 3, u = slot & 7;
    const int kk0 = (u ^ (n & 7)) << 3;  // 8 consecutive kk per slot
    unsigned int w[4];
#pragma unroll
    for (int q = 0; q < 4; ++q) {
      const unsigned int lo = lds[(kk0 + 2 * q + 0) * 136 + n];
      const unsigned int hi = lds[(kk0 + 2 * q + 1) * 136 + n];
      w[q] = lo | (hi << 16);
    }
    *reinterpret_cast<uint4*>(dst + slot * 16) = make_uint4(w[0], w[1], w[2], w[3]);
  }
}

// ---------------------------------------------------------------------------
// Main fused kernel. 512 threads = 8 waves, wave tile 16 rows x 128 cols
// (acc = 32 VGPR). Block tile 128 rows x 128 cols of one j.
// All 4 K-slices (64KB) staged ONCE at block start, slice-ordered; per-slice
// readiness via counted vmcnt + barrier. No restage, no lgkm drains; after
// the 4th barrier everything free-runs (slice-3 MFMA + stores).
// ---------------------------------------------------------------------------
__global__ __launch_bounds__(512, 4) void fused_mlp(
    const float* __restrict__ input, const int* __restrict__ validity,
    const float* __restrict__ W1, const float* __restrict__ b1,
    const float* __restrict__ b2, const unsigned char* __restrict__ w2t,
    float* __restrict__ out) {
  // 64KB W2 (4 slices) + 4KB W1 + 1KB b1 = 70656 bytes.
  // (Round-3 bug: was 69632 -> b1 staging wrote past the allocation.)
  __shared__ __align__(16) unsigned char smem[70656];
  const int bx = blockIdx.x;   // row tile (128 rows)
  const int by = blockIdx.y;   // j*2+ch
  const int j = by >> 1, ch = by & 1;
  const int tid = threadIdx.x;
  const int wid = tid >> 6;
  const int lane = tid & 63;
  const int l15 = lane & 15, lg = lane >> 4;
  const int rowbase = (bx << 7) + (wid << 4);
  const int row = rowbase + l15;

  // ---- prologue global loads: ALL issued before the stages ----
  const float* ip = input + ((size_t)row * 32 + j) * 3;
  const float x0 = ip[0], x1 = ip[1], x2 = ip[2];
  const float x3 = (float)validity[row * 32 + j];
  const float* b2j = b2 + (j << 8) + (ch << 7) + l15;
  float b2v[8];
#pragma unroll
  for (int nf = 0; nf < 8; ++nf) b2v[nf] = b2j[nf << 4];
  float4 wst = make_float4(0.f, 0.f, 0.f, 0.f);
  if (tid < 320) {
    const float* ws = (tid < 256) ? (W1 + (j << 10) + (tid << 2))
                                  : (b1 + (j << 8) + ((tid - 256) << 2));
    wst = *reinterpret_cast<const float4*>(ws);
  }

  // ---- single-shot stage of all 4 W2 slices, slice-ordered (2 instrs/slice)
  const unsigned char* w2tj = w2t + ((size_t)by << 16);
#pragma unroll
  for (int it = 0; it < 8; ++it) {
    const int off = ((it << 3) + wid) << 10;  // 1KB per wave-instr
    __builtin_amdgcn_global_load_lds(
        (const AS1 unsigned int*)(w2tj + off + lane * 16),
        (AS3 unsigned int*)(smem + off), 16, 0, 0);
  }

  // ---- W1/b1 -> LDS (lgkm domain; keeps JIT reads off the vmcnt counter)
  if (tid < 320) *reinterpret_cast<float4*>(smem + 65536 + (tid << 4)) = wst;

  // acc init = bias
  f32x4 acc[8];
#pragma unroll
  for (int nf = 0; nf < 8; ++nf)
    acc[nf] = f32x4{b2v[nf], b2v[nf], b2v[nf], b2v[nf]};

  asm volatile("s_waitcnt lgkmcnt(0)" ::: "memory");  // W1 ds_writes visible
  __builtin_amdgcn_s_barrier();

  // ---- precomputed LDS bases; all loop reads use immediate offsets ----
  const unsigned char* w1base = smem + 65536 + (lg << 5);
  const int q0 = (lg << 4) ^ ((l15 & 7) << 4);
  const unsigned char* rA = smem + l15 * 128 + q0;
  const unsigned char* rB = smem + l15 * 128 + (q0 ^ 64);

  const size_t colbase = (size_t)(j << 8) + (ch << 7) + l15;
  float* outp = out + (size_t)(rowbase + (lg << 2)) * 8192 + colbase;

#pragma unroll
  for (int s = 0; s < 4; ++s) {
    // JIT layer-1 A-fragments for kf = 2s, 2s+1 (W1/b1 from LDS, lgkm only)
    bf16x8 af[2];
#pragma unroll
    for (int kf2 = 0; kf2 < 2; ++kf2) {
      const int kf = 2 * s + kf2;
#pragma unroll
      for (int half = 0; half < 2; ++half) {
        const int im = kf * 128 + half * 16;
        const f32x4 w0 = *reinterpret_cast<const f32x4*>(w1base + im);
        const f32x4 w1v = *reinterpret_cast<const f32x4*>(w1base + 1024 + im);
        const f32x4 w2v = *reinterpret_cast<const f32x4*>(w1base + 2048 + im);
        const f32x4 w3v = *reinterpret_cast<const f32x4*>(w1base + 3072 + im);
        const f32x4 bb = *reinterpret_cast<const f32x4*>(w1base + 4096 + im);
#pragma unroll
        for (int i = 0; i < 4; ++i) {
          float z = bb[i];
          z = fmaf(x0, w0[i], z);
          z = fmaf(x1, w1v[i], z);
          z = fmaf(x2, w2v[i], z);
          z = fmaf(x3, w3v[i], z);
          const float h = z * __builtin_amdgcn_rcpf(1.0f + __expf(-z));
          af[kf2][half * 4 + i] = (short)f2bf(h);
        }
      }
    }

    // slice s staged? counted vmcnt: 2 stage-instrs per slice remain per step
    if (s == 0)      asm volatile("s_waitcnt vmcnt(6)" ::: "memory");
    else if (s == 1) asm volatile("s_waitcnt vmcnt(4)" ::: "memory");
    else if (s == 2) asm volatile("s_waitcnt vmcnt(2)" ::: "memory");
    else             asm volatile("s_waitcnt vmcnt(0)" ::: "memory");
    __builtin_amdgcn_s_barrier();

    const int base = s << 14;
#pragma unroll
    for (int nf = 0; nf < 8; ++nf) {
      const bf16x8 bf0 = *reinterpret_cast<const bf16x8*>(rA + base + nf * 2048);
      const bf16x8 bf1 = *reinterpret_cast<const bf16x8*>(rB + base + nf * 2048);
      acc[nf] = __builtin_amdgcn_mfma_f32_16x16x32_bf16(af[0], bf0, acc[nf], 0, 0, 0);
      acc[nf] = __builtin_amdgcn_mfma_f32_16x16x32_bf16(af[1], bf1, acc[nf], 0, 0, 0);
    }
  }

  // ---- epilogue (free-running; no barrier since last sync) ----
#pragma unroll
  for (int r = 0; r < 4; ++r) {
    float* pr = outp + (size_t)r * 8192;
#pragma unroll
    for (int nf = 0; nf < 8; ++nf) pr[nf << 4] = acc[nf][r];
  }
}

extern "C" void kernel_launch(void* const* d_in, const int* in_sizes, int n_in,
                              void* d_out, int out_size, void* d_ws, size_t ws_size,
                              hipStream_t stream) {
  (void)in_sizes; (void)n_in; (void)out_size; (void)ws_size;
  const float* input    = (const float*)d_in[0];
  const int*   validity = (const int*)d_in[1];
  const float* W1       = (const float*)d_in[2];
  const float* b1       = (const float*)d_in[3];
  const float* W2       = (const float*)d_in[4];
  const float* b2       = (const float*)d_in[5];
  float* out = (float*)d_out;
  unsigned char* w2t = (unsigned char*)d_ws;  // 4 MB: 64 x 64KB

  prep_w2t<<<dim3(4, 64), 256, 0, stream>>>(W2, w2t);
  fused_mlp<<<dim3(64, 64), 512, 0, stream>>>(input, validity, W1, b1, b2, w2t, out);
}

// Round 5
// 89.461 us; speedup vs baseline: 1.4857x; 1.1001x over previous
//
#include <hip/hip_runtime.h>

typedef short bf16x8 __attribute__((ext_vector_type(8)));
typedef float f32x4 __attribute__((ext_vector_type(4)));

#define AS1 __attribute__((address_space(1)))
#define AS3 __attribute__((address_space(3)))

__device__ __forceinline__ unsigned short f2bf(float f) {
  unsigned int u = __builtin_bit_cast(unsigned int, f);
  return (unsigned short)((u + 0x8000u) >> 16);
}

// ---------------------------------------------------------------------------
// Prep: W2 [J][256][256] f32 -> w2t [j*2+ch][4 slices][128 cols][128B] bf16,
// swizzled: byte(n, kk) = n*128 + ((2*kk) ^ ((n&7)<<4)), n in [0,128),
// kk in [0,64). Linear image for global_load_lds + conflict-free ds_read_b128.
// ---------------------------------------------------------------------------
__global__ __launch_bounds__(256) void prep_w2t(const float* __restrict__ W2,
                                                unsigned char* __restrict__ w2t) {
  const int s = blockIdx.x;    // k-slice 0..3
  const int jc = blockIdx.y;   // j*2+ch
  const int j = jc >> 1, ch = jc & 1;
  const int t = threadIdx.x;
  __shared__ unsigned short lds[64 * 136];  // [kk][n], padded

  const float* src = W2 + (size_t)j * 65536 + (size_t)(s * 64) * 256 + ch * 128;
#pragma unroll
  for (int i = 0; i < 8; ++i) {
    const int idx4 = i * 256 + t;        // 2048 float4s = 64kk x 128n
    const int kk = idx4 >> 5;
    const int n4 = (idx4 & 31) << 2;
    const float4 v = *reinterpret_cast<const float4*>(src + kk * 256 + n4);
    unsigned short* p = &lds[kk * 136 + n4];
    p[0] = f2bf(v.x); p[1] = f2bf(v.y); p[2] = f2bf(v.z); p[3] = f2bf(v.w);
  }
  __syncthreads();

  unsigned char* dst = w2t + (((size_t)jc * 4 + s) << 14);
#pragma unroll
  for (int i = 0; i < 4; ++i) {
    const int slot = i * 256 + t;        // 1024 16B slots
    const int n = slot >> 3, u = slot & 7;
    const int kk0 = (u ^ (n & 7)) << 3;  // 8 consecutive kk per slot
    unsigned int w[4];
#pragma unroll
    for (int q = 0; q < 4; ++q) {
      const unsigned int lo = lds[(kk0 + 2 * q + 0) * 136 + n];
      const unsigned int hi = lds[(kk0 + 2 * q + 1) * 136 + n];
      w[q] = lo | (hi << 16);
    }
    *reinterpret_cast<uint4*>(dst + slot * 16) = make_uint4(w[0], w[1], w[2], w[3]);
  }
}

// ---------------------------------------------------------------------------
// Main fused kernel. 512 threads = 8 waves, wave tile 32 rows x 128 cols
// (2 m-frags: each B ds_read feeds 2 MFMAs -> half the LDS B traffic of a
// 16-row wave). Block tile 256 rows x 128 cols of one (j,ch).
// All 4 K-slices (64KB) staged ONCE at block start, slice-ordered; per-slice
// readiness via counted vmcnt + barrier. No restage, no lgkm drains.
// ---------------------------------------------------------------------------
__global__ __launch_bounds__(512, 4) void fused_mlp(
    const float* __restrict__ input, const int* __restrict__ validity,
    const float* __restrict__ W1, const float* __restrict__ b1,
    const float* __restrict__ b2, const unsigned char* __restrict__ w2t,
    float* __restrict__ out) {
  // 64KB W2 (4 slices) + 4KB W1 + 1KB b1 = 70656 bytes.
  __shared__ __align__(16) unsigned char smem[70656];
  const int bx = blockIdx.x;   // row tile (256 rows)
  const int by = blockIdx.y;   // j*2+ch
  const int j = by >> 1, ch = by & 1;
  const int tid = threadIdx.x;
  const int wid = tid >> 6;
  const int lane = tid & 63;
  const int l15 = lane & 15, lg = lane >> 4;
  const int rowbase = (bx << 8) + (wid << 5);  // wave owns 32 rows

  // ---- prologue global loads: ALL issued before the stages ----
  float xr[2][4];
#pragma unroll
  for (int mf = 0; mf < 2; ++mf) {
    const int row = rowbase + mf * 16 + l15;
    const float* ip = input + ((size_t)row * 32 + j) * 3;
    xr[mf][0] = ip[0]; xr[mf][1] = ip[1]; xr[mf][2] = ip[2];
    xr[mf][3] = (float)validity[row * 32 + j];
  }
  const float* b2j = b2 + (j << 8) + (ch << 7) + l15;
  float b2v[8];
#pragma unroll
  for (int nf = 0; nf < 8; ++nf) b2v[nf] = b2j[nf << 4];
  float4 wst = make_float4(0.f, 0.f, 0.f, 0.f);
  if (tid < 320) {
    const float* ws = (tid < 256) ? (W1 + (j << 10) + (tid << 2))
                                  : (b1 + (j << 8) + ((tid - 256) << 2));
    wst = *reinterpret_cast<const float4*>(ws);
  }

  // ---- single-shot stage of all 4 W2 slices, slice-ordered (2 instrs/slice)
  const unsigned char* w2tj = w2t + ((size_t)by << 16);
#pragma unroll
  for (int it = 0; it < 8; ++it) {
    const int off = ((it << 3) + wid) << 10;  // 1KB per wave-instr
    __builtin_amdgcn_global_load_lds(
        (const AS1 unsigned int*)(w2tj + off + lane * 16),
        (AS3 unsigned int*)(smem + off), 16, 0, 0);
  }

  // ---- W1/b1 -> LDS (lgkm domain; keeps JIT reads off the vmcnt counter)
  if (tid < 320) *reinterpret_cast<float4*>(smem + 65536 + (tid << 4)) = wst;

  // acc init = bias
  f32x4 acc[2][8];
#pragma unroll
  for (int nf = 0; nf < 8; ++nf) {
    acc[0][nf] = f32x4{b2v[nf], b2v[nf], b2v[nf], b2v[nf]};
    acc[1][nf] = acc[0][nf];
  }

  asm volatile("s_waitcnt lgkmcnt(0)" ::: "memory");  // W1 ds_writes visible
  __builtin_amdgcn_s_barrier();

  // ---- precomputed LDS bases; all loop reads use immediate offsets ----
  const unsigned char* w1base = smem + 65536 + (lg << 5);
  const int q0 = (lg << 4) ^ ((l15 & 7) << 4);
  const unsigned char* rA = smem + l15 * 128 + q0;
  const unsigned char* rB = smem + l15 * 128 + (q0 ^ 64);

  const size_t colbase = (size_t)(j << 8) + (ch << 7) + l15;

#pragma unroll
  for (int s = 0; s < 4; ++s) {
    // JIT layer-1 A-fragments for kf = 2s, 2s+1; W1/b1 broadcast reads from
    // LDS are shared by both m-frags (half the per-row read cost of a 16-row
    // wave). VALU here overlaps other waves' MFMA + the in-flight stages.
    bf16x8 af[2][2];  // [kf2][mf]
#pragma unroll
    for (int kf2 = 0; kf2 < 2; ++kf2) {
      const int kf = 2 * s + kf2;
#pragma unroll
      for (int half = 0; half < 2; ++half) {
        const int im = kf * 128 + half * 16;
        const f32x4 w0 = *reinterpret_cast<const f32x4*>(w1base + im);
        const f32x4 w1v = *reinterpret_cast<const f32x4*>(w1base + 1024 + im);
        const f32x4 w2v = *reinterpret_cast<const f32x4*>(w1base + 2048 + im);
        const f32x4 w3v = *reinterpret_cast<const f32x4*>(w1base + 3072 + im);
        const f32x4 bb = *reinterpret_cast<const f32x4*>(w1base + 4096 + im);
#pragma unroll
        for (int mf = 0; mf < 2; ++mf) {
#pragma unroll
          for (int i = 0; i < 4; ++i) {
            float z = bb[i];
            z = fmaf(xr[mf][0], w0[i], z);
            z = fmaf(xr[mf][1], w1v[i], z);
            z = fmaf(xr[mf][2], w2v[i], z);
            z = fmaf(xr[mf][3], w3v[i], z);
            const float h = z * __builtin_amdgcn_rcpf(1.0f + __expf(-z));
            af[kf2][mf][half * 4 + i] = (short)f2bf(h);
          }
        }
      }
    }

    // slice s staged? counted vmcnt: 2 stage-instrs per slice remain per step
    if (s == 0)      asm volatile("s_waitcnt vmcnt(6)" ::: "memory");
    else if (s == 1) asm volatile("s_waitcnt vmcnt(4)" ::: "memory");
    else if (s == 2) asm volatile("s_waitcnt vmcnt(2)" ::: "memory");
    else             asm volatile("s_waitcnt vmcnt(0)" ::: "memory");
    __builtin_amdgcn_s_barrier();

    const int base = s << 14;
#pragma unroll
    for (int nf = 0; nf < 8; ++nf) {
      const bf16x8 bf0 = *reinterpret_cast<const bf16x8*>(rA + base + nf * 2048);
      const bf16x8 bf1 = *reinterpret_cast<const bf16x8*>(rB + base + nf * 2048);
      acc[0][nf] = __builtin_amdgcn_mfma_f32_16x16x32_bf16(af[0][0], bf0, acc[0][nf], 0, 0, 0);
      acc[1][nf] = __builtin_amdgcn_mfma_f32_16x16x32_bf16(af[0][1], bf0, acc[1][nf], 0, 0, 0);
      acc[0][nf] = __builtin_amdgcn_mfma_f32_16x16x32_bf16(af[1][0], bf1, acc[0][nf], 0, 0, 0);
      acc[1][nf] = __builtin_amdgcn_mfma_f32_16x16x32_bf16(af[1][1], bf1, acc[1][nf], 0, 0, 0);
    }
  }

  // ---- epilogue (free-running; no barrier since last sync) ----
#pragma unroll
  for (int mf = 0; mf < 2; ++mf) {
#pragma unroll
    for (int r = 0; r < 4; ++r) {
      const int row = rowbase + mf * 16 + (lg << 2) + r;
      float* pr = out + (size_t)row * 8192 + colbase;
#pragma unroll
      for (int nf = 0; nf < 8; ++nf) pr[nf << 4] = acc[mf][nf][r];
    }
  }
}

extern "C" void kernel_launch(void* const* d_in, const int* in_sizes, int n_in,
                              void* d_out, int out_size, void* d_ws, size_t ws_size,
                              hipStream_t stream) {
  (void)in_sizes; (void)n_in; (void)out_size; (void)ws_size;
  const float* input    = (const float*)d_in[0];
  const int*   validity = (const int*)d_in[1];
  const float* W1       = (const float*)d_in[2];
  const float* b1       = (const float*)d_in[3];
  const float* W2       = (const float*)d_in[4];
  const float* b2       = (const float*)d_in[5];
  float* out = (float*)d_out;
  unsigned char* w2t = (unsigned char*)d_ws;  // 4 MB: 64 x 64KB

  prep_w2t<<<dim3(4, 64), 256, 0, stream>>>(W2, w2t);
  fused_mlp<<<dim3(32, 64), 512, 0, stream>>>(input, validity, W1, b1, b2, w2t, out);
}